// Round 4
// baseline (327.482 us; speedup 1.0000x reference)
//
#include <hip/hip_runtime.h>
#include <hip/hip_bf16.h>

#define T_DIM 200
#define U_DIM 100
#define U1    101
#define H_DIM 320
#define K_INNER 512
#define V_DIM 1000
#define B_DIM 4
#define DP_PITCH 128
#define ND 300            // diagonals d = t+u in [0, 299]

typedef unsigned short ushort_t;
typedef unsigned int uint32;

typedef short bfrag8 __attribute__((ext_vector_type(8)));
typedef float ffrag4 __attribute__((ext_vector_type(4)));

#define LOG2E 1.4426950408889634f
#define LN2   0.6931471805599453f

__device__ __forceinline__ uint32 pk_bf16(float a, float b) {
  __hip_bfloat162 h = __float22bfloat162_rn(make_float2(a, b));
  return *(uint32*)&h;
}

__device__ __forceinline__ float tanh_fast(float x) {
  float e = __expf(2.0f * x);                 // inf-safe: e=inf -> 1, e=0 -> -1
  return 1.0f - __fdividef(2.0f, e + 1.0f);
}

// ---------------- fused prep:
//   blocks [0,100):   h_enc projection (8 rows each)
//   blocks [100,151): h_dec projection (8 rows each)
//   blocks [151,215): W2 transpose-pack -> W2f[kchunk 64][n 1024][8 shorts]
__global__ __launch_bounds__(512)
void prep_kernel(const float* __restrict__ enc, const float* __restrict__ dec,
                 const float* __restrict__ W1, const float* __restrict__ W2,
                 float* __restrict__ hEnc, float* __restrict__ hDec,
                 ushort_t* __restrict__ W2f)
{
  __shared__ union { float sIn[8][H_DIM]; float sW[8][1024]; } sh;
  const int tid = threadIdx.x;
  const int blk = blockIdx.x;

  if (blk < 151) {
    const float* inp; float* outp; int nRows, rowOff, b0;
    if (blk < 100) { inp = enc; outp = hEnc; nRows = B_DIM * T_DIM; rowOff = 0;     b0 = blk; }
    else           { inp = dec; outp = hDec; nRows = B_DIM * U1;    rowOff = H_DIM; b0 = blk - 100; }
    const int r0 = b0 * 8;
    for (int i = tid; i < 8 * H_DIM; i += 512) {
      int r = i / H_DIM, k = i - r * H_DIM;
      int rr = r0 + r;
      sh.sIn[r][k] = (rr < nRows) ? inp[(size_t)rr * H_DIM + k] : 0.0f;
    }
    __syncthreads();
    const int c = tid;  // 0..511
    float acc[8];
#pragma unroll
    for (int r = 0; r < 8; ++r) acc[r] = 0.0f;
    const float* Wp = W1 + (size_t)rowOff * K_INNER + c;
    for (int k = 0; k < H_DIM; k += 4) {
      float w0 = Wp[(size_t)(k + 0) * K_INNER];
      float w1 = Wp[(size_t)(k + 1) * K_INNER];
      float w2 = Wp[(size_t)(k + 2) * K_INNER];
      float w3 = Wp[(size_t)(k + 3) * K_INNER];
#pragma unroll
      for (int r = 0; r < 8; ++r) {
        float4 s = *(const float4*)&sh.sIn[r][k];
        acc[r] = fmaf(s.w, w3, fmaf(s.z, w2, fmaf(s.y, w1, fmaf(s.x, w0, acc[r]))));
      }
    }
#pragma unroll
    for (int r = 0; r < 8; ++r) {
      int rr = r0 + r;
      if (rr < nRows) outp[(size_t)rr * K_INNER + c] = acc[r];
    }
  } else {
    // W2 pack: kchunk kc covers k in [kc*8, kc*8+8); LDS transpose for coalesced R+W
    const int kc = blk - 151;
    for (int i = tid; i < 8 * 1024; i += 512) {
      int r = i >> 10, n = i & 1023;
      sh.sW[r][n] = (n < V_DIM) ? W2[(size_t)(kc * 8 + r) * V_DIM + n] : 0.0f;
    }
    __syncthreads();
#pragma unroll
    for (int h = 0; h < 2; ++h) {
      int n = tid + h * 512;
      uint4 pk;
      pk.x = pk_bf16(sh.sW[0][n], sh.sW[1][n]);
      pk.y = pk_bf16(sh.sW[2][n], sh.sW[3][n]);
      pk.z = pk_bf16(sh.sW[4][n], sh.sW[5][n]);
      pk.w = pk_bf16(sh.sW[6][n], sh.sW[7][n]);
      *(uint4*)&W2f[((size_t)kc * 1024 + n) * 8] = pk;
    }
  }
}

// ---------------- fused joint, 32-row tile (8t x 4u), 32KB LDS -> 4-5 blocks/CU.
// Swizzle: granule (row, kchunk) at slot (kchunk + row) & 63 (classic pad-equivalent).
// Staging thread map: row = tid>>3, c = tid&7, granules G = c + 8g -> any 8
// consecutive lanes hit 8 distinct bank groups on writes; A-reads likewise.
__global__ __launch_bounds__(256, 4)
void joint_kernel(const float* __restrict__ hEnc, const float* __restrict__ hDec,
                  const float* __restrict__ b1, const ushort_t* __restrict__ W2f,
                  const float* __restrict__ b2, const int* __restrict__ tokens,
                  float* __restrict__ blankD, float* __restrict__ labelD)
{
  __shared__ union SU {
    ushort_t X[32 * K_INNER];     // 32 rows x 64 granules of 8 bf16, swizzled (32KB)
    float red[4][32][4];
  } sh;

  const int tid = threadIdx.x;
  const int b  = blockIdx.z;
  const int t0 = blockIdx.y * 8;    // 25 blocks cover 200 exactly
  const int u0 = blockIdx.x * 4;    // 26 blocks cover 104 >= 101

  // ---- X staging: row = tt*4+uu (32 rows); thread (row=tid>>3, c=tid&7) writes G=c+8g
  {
    const int row = tid >> 3;             // 0..31
    const int c = tid & 7;
    const int tt = row >> 2, uu = row & 3;
    const int tcl = t0 + tt;                       // always < 200
    const int ucl = min(u0 + uu, U1 - 1);
    const float* er = hEnc + (size_t)(b * T_DIM + tcl) * K_INNER;
    const float* dr = hDec + (size_t)(b * U1 + ucl) * K_INNER;
#pragma unroll
    for (int g = 0; g < 8; ++g) {
      const int G = c + 8 * g;
      const int k = G << 3;
      float4 e0 = *(const float4*)(er + k);
      float4 e1 = *(const float4*)(er + k + 4);
      float4 d0 = *(const float4*)(dr + k);
      float4 d1 = *(const float4*)(dr + k + 4);
      float4 c0 = *(const float4*)(b1 + k);
      float4 c1 = *(const float4*)(b1 + k + 4);
      uint4 pk;
      pk.x = pk_bf16(tanh_fast(e0.x + d0.x + c0.x), tanh_fast(e0.y + d0.y + c0.y));
      pk.y = pk_bf16(tanh_fast(e0.z + d0.z + c0.z), tanh_fast(e0.w + d0.w + c0.w));
      pk.z = pk_bf16(tanh_fast(e1.x + d1.x + c1.x), tanh_fast(e1.y + d1.y + c1.y));
      pk.w = pk_bf16(tanh_fast(e1.z + d1.z + c1.z), tanh_fast(e1.w + d1.w + c1.w));
      const int slot = (G + row) & 63;
      *(uint4*)&sh.X[row * K_INNER + (slot << 3)] = pk;
    }
  }
  __syncthreads();

  const int wave = tid >> 6;
  const int lane = tid & 63;
  const int l15 = lane & 15;
  const int quad = lane >> 4;

  float sumexp[2][4], labelA[2][4], blankV[2][4];
#pragma unroll
  for (int i = 0; i < 2; ++i)
#pragma unroll
    for (int j = 0; j < 4; ++j) { sumexp[i][j] = 0.0f; labelA[i][j] = 0.0f; blankV[i][j] = 0.0f; }

  int tokv[4];
#pragma unroll
  for (int j = 0; j < 4; ++j)
    tokv[j] = (u0 + j < U_DIM) ? tokens[b * U_DIM + u0 + j] : -1;

#pragma unroll 1
  for (int ct = 0; ct < 4; ++ct) {
    const int nbase = ct * 256 + wave * 64;
    ffrag4 acc[2][4];
    ffrag4 zero4 = {0.0f, 0.0f, 0.0f, 0.0f};
#pragma unroll
    for (int rb = 0; rb < 2; ++rb)
#pragma unroll
      for (int cb = 0; cb < 4; ++cb) acc[rb][cb] = zero4;

    // prefetch ks=0 B-frags
    bfrag8 bvC[4];
#pragma unroll
    for (int cb = 0; cb < 4; ++cb) {
      const int n = nbase + cb * 16 + l15;
      bvC[cb] = *(const bfrag8*)(W2f + ((size_t)quad * 1024 + n) * 8);
    }

#pragma unroll 4
    for (int ks = 0; ks < 16; ++ks) {
      const int kchunk = ks * 4 + quad;
      bfrag8 av[2];
#pragma unroll
      for (int rb = 0; rb < 2; ++rb) {
        const int m = rb * 16 + l15;
        const int slot = (kchunk + m) & 63;
        av[rb] = *(const bfrag8*)&sh.X[m * K_INNER + (slot << 3)];
      }
      bfrag8 bvN[4];
      if (ks < 15) {
#pragma unroll
        for (int cb = 0; cb < 4; ++cb) {
          const int n = nbase + cb * 16 + l15;
          bvN[cb] = *(const bfrag8*)(W2f + ((size_t)(kchunk + 4) * 1024 + n) * 8);
        }
      }
#pragma unroll
      for (int rb = 0; rb < 2; ++rb)
#pragma unroll
        for (int cb = 0; cb < 4; ++cb)
          acc[rb][cb] = __builtin_amdgcn_mfma_f32_16x16x32_bf16(av[rb], bvC[cb], acc[rb][cb], 0, 0, 0);
#pragma unroll
      for (int cb = 0; cb < 4; ++cb) bvC[cb] = bvN[cb];
    }

    // epilogue: online sum(exp) via exp2, raw label capture (b2 folded at the end)
#pragma unroll
    for (int cb = 0; cb < 4; ++cb) {
      const int v = nbase + cb * 16 + l15;
      const float b2v = (v < V_DIM) ? b2[v] : -1e30f;
      const float b2s = b2v * LOG2E;
#pragma unroll
      for (int rb = 0; rb < 2; ++rb)
#pragma unroll
        for (int reg = 0; reg < 4; ++reg) {
          float a = acc[rb][cb][reg];
          sumexp[rb][reg] += exp2f(fmaf(a, LOG2E, b2s));
          labelA[rb][reg] += (v == tokv[reg]) ? a : 0.0f;
        }
    }
    if (nbase == 0) {   // wave 0, ct 0: v==0 column lives on l15==0 lanes of cb 0
#pragma unroll
      for (int rb = 0; rb < 2; ++rb)
#pragma unroll
        for (int reg = 0; reg < 4; ++reg) blankV[rb][reg] = acc[rb][0][reg];
    }
  }

#pragma unroll
  for (int mask = 1; mask <= 8; mask <<= 1) {
#pragma unroll
    for (int rb = 0; rb < 2; ++rb)
#pragma unroll
      for (int reg = 0; reg < 4; ++reg) {
        sumexp[rb][reg] += __shfl_xor(sumexp[rb][reg], mask, 64);
        labelA[rb][reg] += __shfl_xor(labelA[rb][reg], mask, 64);
      }
  }

  __syncthreads();   // X reads done -> reuse union as red[]
  if (l15 == 0) {
#pragma unroll
    for (int rb = 0; rb < 2; ++rb)
#pragma unroll
      for (int reg = 0; reg < 4; ++reg) {
        int row = rb * 16 + quad * 4 + reg;
        sh.red[wave][row][0] = sumexp[rb][reg];
        sh.red[wave][row][1] = blankV[rb][reg];
        sh.red[wave][row][2] = labelA[rb][reg];
      }
  }
  __syncthreads();
  if (tid < 32) {
    float S  = sh.red[0][tid][0] + sh.red[1][tid][0] + sh.red[2][tid][0] + sh.red[3][tid][0];
    float Bl = sh.red[0][tid][1] + sh.red[1][tid][1] + sh.red[2][tid][1] + sh.red[3][tid][1];
    float Lb = sh.red[0][tid][2] + sh.red[1][tid][2] + sh.red[2][tid][2] + sh.red[3][tid][2];
    int t = t0 + (tid >> 2);
    int u = u0 + (tid & 3);
    if (u < U1) {
      float lse2 = __log2f(S);                 // S = sum(exp(logit))
      int tok = (u < U_DIM) ? tokens[b * U_DIM + u] : 0;
      int d = t + u;
      size_t idx = ((size_t)b * ND + d) * DP_PITCH + u;
      // store log2-domain log-probs for the DP
      blankD[idx] = (Bl + b2[0])   * LOG2E - lse2;
      labelD[idx] = (Lb + b2[tok]) * LOG2E - lse2;
    }
  }
}

// ---------------- RNNT DP over diagonals, log2 domain, named-register pipeline
__global__ __launch_bounds__(256)
void dp_kernel(const float* __restrict__ blankD, const float* __restrict__ labelD,
               const int* __restrict__ outLen, const int* __restrict__ tokLen,
               float* __restrict__ outLoss)
{
  __shared__ float llsh[B_DIM];
  const int tid = threadIdx.x;
  const int wv = tid >> 6;
  const int lane = tid & 63;
  const float* bD = blankD + (size_t)wv * ND * DP_PITCH;
  const float* lD = labelD + (size_t)wv * ND * DP_PITCH;
  const int tIdx = outLen[wv] - 1;
  const int uIdx = tokLen[wv];
  const int dStar = tIdx + uIdx;
  const float NEG = -1e30f;

  float aE = (lane == 0) ? 0.0f : NEG;   // log2(1) = 0
  float aO = NEG;
  const float blkStar = bD[(size_t)dStar * DP_PITCH + uIdx];
  float ll2 = 0.0f;
  if (dStar == 0 && lane == 0) ll2 = blkStar;

  const int uE = 2 * lane, uO = uE + 1;

#define LDB(dg) (*(const float2*)&bD[(size_t)(dg) * DP_PITCH + uE])
#define LDL(dg) (*(const float2*)&lD[(size_t)(dg) * DP_PITCH + uE])

  float2 B0 = LDB(0), L0 = LDL(0);
  float2 B1 = LDB(1), L1 = LDL(1);
  float2 B2 = LDB(2), L2 = LDL(2);
  float2 B3 = LDB(3), L3 = LDL(3);

#define DPSTEP(d, Bv, Lv)                                                    \
  {                                                                          \
    float aO_up = __shfl_up(aO, 1, 64);                                      \
    if (lane == 0) aO_up = NEG;                                              \
    float labUp = __shfl_up(Lv.y, 1, 64);                                    \
    float bt0 = aE + Bv.x, lt0 = aO_up + labUp;                              \
    float mx0 = fmaxf(bt0, lt0), mn0 = fminf(bt0, lt0);                      \
    float r0 = mx0 + __log2f(1.0f + exp2f(mn0 - mx0));                       \
    int te = (d) - uE;                                                       \
    float nE = ((uE <= U_DIM) && (te >= 0) && (te < T_DIM)) ? r0 : NEG;      \
    float bt1 = aO + Bv.y, lt1 = aE + Lv.x;                                  \
    float mx1 = fmaxf(bt1, lt1), mn1 = fminf(bt1, lt1);                      \
    float r1 = mx1 + __log2f(1.0f + exp2f(mn1 - mx1));                       \
    int to = (d) - uO;                                                       \
    float nO = ((uO <= U_DIM) && (to >= 0) && (to < T_DIM)) ? r1 : NEG;      \
    aE = nE; aO = nO;                                                        \
    if ((d) == dStar)                                                        \
      ll2 = (uIdx == uE) ? nE + blkStar : ((uIdx == uO) ? nO + blkStar : ll2); \
  }

  // groups of 4: base = 1,5,...,293 covers d = 1..296; tail d = 297..299
  for (int base = 1; base <= 293; base += 4) {
    DPSTEP(base + 0, B0, L0); B0 = LDB(base + 3); L0 = LDL(base + 3);
    DPSTEP(base + 1, B1, L1); B1 = LDB(base + 4); L1 = LDL(base + 4);
    DPSTEP(base + 2, B2, L2); B2 = LDB(base + 5); L2 = LDL(base + 5);
    DPSTEP(base + 3, B3, L3); B3 = LDB(base + 6); L3 = LDL(base + 6);
  }
  DPSTEP(297, B0, L0);
  DPSTEP(298, B1, L1);
  DPSTEP(299, B2, L2);

#undef DPSTEP
#undef LDB
#undef LDL

#pragma unroll
  for (int mask = 1; mask < 64; mask <<= 1) ll2 += __shfl_xor(ll2, mask, 64);
  if (lane == 0) llsh[wv] = ll2;
  __syncthreads();
  if (tid == 0)
    outLoss[0] = -(llsh[0] + llsh[1] + llsh[2] + llsh[3]) * 0.25f * LN2;
}

// ---------------- launch
extern "C" void kernel_launch(void* const* d_in, const int* in_sizes, int n_in,
                              void* d_out, int out_size, void* d_ws, size_t ws_size,
                              hipStream_t stream)
{
  const float* enc    = (const float*)d_in[0];
  const float* dec    = (const float*)d_in[1];
  const int*   tokens = (const int*)d_in[2];
  const int*   outLen = (const int*)d_in[3];
  const int*   tokLen = (const int*)d_in[4];
  const float* W1     = (const float*)d_in[5];
  const float* b1     = (const float*)d_in[6];
  const float* W2     = (const float*)d_in[7];
  const float* b2     = (const float*)d_in[8];
  float* out = (float*)d_out;

  char* ws = (char*)d_ws;
  float*    hEnc   = (float*)(ws + 0);           // 800*512*4   = 1,638,400
  float*    hDec   = (float*)(ws + 1638400);     // 404*512*4   =   827,392
  ushort_t* W2f    = (ushort_t*)(ws + 2465792);  // 64*1024*8*2 = 1,048,576
  float*    blankD = (float*)(ws + 3514368);     // 4*300*128*4 =   614,400
  float*    labelD = (float*)(ws + 4128768);     // 4*300*128*4 =   614,400  (end 4,743,168)

  prep_kernel<<<dim3(215), dim3(512), 0, stream>>>(enc, dec, W1, W2, hEnc, hDec, W2f);
  joint_kernel<<<dim3(26, 25, B_DIM), dim3(256), 0, stream>>>(hEnc, hDec, b1, W2f, b2, tokens, blankD, labelD);
  dp_kernel<<<dim3(1), dim3(256), 0, stream>>>(blankD, labelD, outLen, tokLen, out);
}

// Round 5
// 272.691 us; speedup vs baseline: 1.2009x; 1.2009x over previous
//
#include <hip/hip_runtime.h>
#include <hip/hip_bf16.h>

#define T_DIM 200
#define U_DIM 100
#define U1    101
#define H_DIM 320
#define K_INNER 512
#define V_DIM 1000
#define B_DIM 4
#define DP_PITCH 128
#define ND 300            // diagonals d = t+u in [0, 299]
#define ROWS 48           // 12 t x 4 u per block

typedef unsigned short ushort_t;
typedef unsigned int uint32;

typedef short bfrag8 __attribute__((ext_vector_type(8)));
typedef float ffrag4 __attribute__((ext_vector_type(4)));

#define LOG2E 1.4426950408889634f
#define LN2   0.6931471805599453f

__device__ __forceinline__ uint32 pk_bf16(float a, float b) {
  __hip_bfloat162 h = __float22bfloat162_rn(make_float2(a, b));
  return *(uint32*)&h;
}

__device__ __forceinline__ float tanh_fast(float x) {
  float e = __expf(2.0f * x);                 // inf-safe: e=inf -> 1, e=0 -> -1
  return 1.0f - __fdividef(2.0f, e + 1.0f);
}

// ---------------- fused prep:
//   blocks [0,100):   h_enc projection (8 rows each)
//   blocks [100,151): h_dec projection (8 rows each)
//   blocks [151,215): W2 transpose-pack -> W2f[kchunk 64][n 1024][8 shorts]
__global__ __launch_bounds__(512)
void prep_kernel(const float* __restrict__ enc, const float* __restrict__ dec,
                 const float* __restrict__ W1, const float* __restrict__ W2,
                 float* __restrict__ hEnc, float* __restrict__ hDec,
                 ushort_t* __restrict__ W2f)
{
  __shared__ union { float sIn[8][H_DIM]; float sW[8][1024]; } sh;
  const int tid = threadIdx.x;
  const int blk = blockIdx.x;

  if (blk < 151) {
    const float* inp; float* outp; int nRows, rowOff, b0;
    if (blk < 100) { inp = enc; outp = hEnc; nRows = B_DIM * T_DIM; rowOff = 0;     b0 = blk; }
    else           { inp = dec; outp = hDec; nRows = B_DIM * U1;    rowOff = H_DIM; b0 = blk - 100; }
    const int r0 = b0 * 8;
    for (int i = tid; i < 8 * H_DIM; i += 512) {
      int r = i / H_DIM, k = i - r * H_DIM;
      int rr = r0 + r;
      sh.sIn[r][k] = (rr < nRows) ? inp[(size_t)rr * H_DIM + k] : 0.0f;
    }
    __syncthreads();
    const int c = tid;  // 0..511
    float acc[8];
#pragma unroll
    for (int r = 0; r < 8; ++r) acc[r] = 0.0f;
    const float* Wp = W1 + (size_t)rowOff * K_INNER + c;
    for (int k = 0; k < H_DIM; k += 4) {
      float w0 = Wp[(size_t)(k + 0) * K_INNER];
      float w1 = Wp[(size_t)(k + 1) * K_INNER];
      float w2 = Wp[(size_t)(k + 2) * K_INNER];
      float w3 = Wp[(size_t)(k + 3) * K_INNER];
#pragma unroll
      for (int r = 0; r < 8; ++r) {
        float4 s = *(const float4*)&sh.sIn[r][k];
        acc[r] = fmaf(s.w, w3, fmaf(s.z, w2, fmaf(s.y, w1, fmaf(s.x, w0, acc[r]))));
      }
    }
#pragma unroll
    for (int r = 0; r < 8; ++r) {
      int rr = r0 + r;
      if (rr < nRows) outp[(size_t)rr * K_INNER + c] = acc[r];
    }
  } else {
    // W2 pack: kchunk kc covers k in [kc*8, kc*8+8); LDS transpose for coalesced R+W
    const int kc = blk - 151;
    for (int i = tid; i < 8 * 1024; i += 512) {
      int r = i >> 10, n = i & 1023;
      sh.sW[r][n] = (n < V_DIM) ? W2[(size_t)(kc * 8 + r) * V_DIM + n] : 0.0f;
    }
    __syncthreads();
#pragma unroll
    for (int h = 0; h < 2; ++h) {
      int n = tid + h * 512;
      uint4 pk;
      pk.x = pk_bf16(sh.sW[0][n], sh.sW[1][n]);
      pk.y = pk_bf16(sh.sW[2][n], sh.sW[3][n]);
      pk.z = pk_bf16(sh.sW[4][n], sh.sW[5][n]);
      pk.w = pk_bf16(sh.sW[6][n], sh.sW[7][n]);
      *(uint4*)&W2f[((size_t)kc * 1024 + n) * 8] = pk;
    }
  }
}

// ---------------- fused joint, 48-row tile (12t x 4u), 48KB LDS -> 3 blocks/CU.
// B (packed W2, 1MB) streams from L2 once per block: 48-row tile cuts per-output
// B-traffic 1.5x vs 32-row (L2->CU bandwidth is the limiting pipe, ~49us floor).
// launch_bounds (256,3): VGPR cap 168 -> no scratch spill (r4's (256,4)/64-VGPR
// config spilled: WRITE_SIZE 31.8MB).
__global__ __launch_bounds__(256, 3)
void joint_kernel(const float* __restrict__ hEnc, const float* __restrict__ hDec,
                  const float* __restrict__ b1, const ushort_t* __restrict__ W2f,
                  const float* __restrict__ b2, const int* __restrict__ tokens,
                  float* __restrict__ blankD, float* __restrict__ labelD)
{
  __shared__ union SU {
    ushort_t X[ROWS * K_INNER];   // 48 rows x 64 granules of 8 bf16, swizzled (48KB)
    float red[4][ROWS][4];
  } sh;

  const int tid = threadIdx.x;
  const int b  = blockIdx.z;
  const int t0 = blockIdx.y * 12;   // 17 blocks cover 200 (last partially redundant, writes guarded)
  const int u0 = blockIdx.x * 4;    // 26 blocks cover 104 >= 101

  // ---- X staging: 3072 granules, 12 per thread; wave handles one row per pass
  // (i 64-aligned per wave -> row uniform, G = lane -> conflict-free writes)
  for (int i = tid; i < ROWS * 64; i += 256) {
    const int row = i >> 6;           // 0..47
    const int G = i & 63;
    const int tcl = min(t0 + (row >> 2), T_DIM - 1);
    const int ucl = min(u0 + (row & 3), U1 - 1);
    const float* er = hEnc + (size_t)(b * T_DIM + tcl) * K_INNER;
    const float* dr = hDec + (size_t)(b * U1 + ucl) * K_INNER;
    const int k = G << 3;
    float4 e0 = *(const float4*)(er + k);
    float4 e1 = *(const float4*)(er + k + 4);
    float4 d0 = *(const float4*)(dr + k);
    float4 d1 = *(const float4*)(dr + k + 4);
    float4 c0 = *(const float4*)(b1 + k);
    float4 c1 = *(const float4*)(b1 + k + 4);
    uint4 pk;
    pk.x = pk_bf16(tanh_fast(e0.x + d0.x + c0.x), tanh_fast(e0.y + d0.y + c0.y));
    pk.y = pk_bf16(tanh_fast(e0.z + d0.z + c0.z), tanh_fast(e0.w + d0.w + c0.w));
    pk.z = pk_bf16(tanh_fast(e1.x + d1.x + c1.x), tanh_fast(e1.y + d1.y + c1.y));
    pk.w = pk_bf16(tanh_fast(e1.z + d1.z + c1.z), tanh_fast(e1.w + d1.w + c1.w));
    const int slot = (G + row) & 63;
    *(uint4*)&sh.X[row * K_INNER + (slot << 3)] = pk;
  }
  __syncthreads();

  const int wave = tid >> 6;
  const int lane = tid & 63;
  const int l15 = lane & 15;
  const int quad = lane >> 4;

  float sumexp[3][4], labelA[3][4], blankV[3][4];
#pragma unroll
  for (int i = 0; i < 3; ++i)
#pragma unroll
    for (int j = 0; j < 4; ++j) { sumexp[i][j] = 0.0f; labelA[i][j] = 0.0f; blankV[i][j] = 0.0f; }

  int tokv[4];
#pragma unroll
  for (int j = 0; j < 4; ++j)
    tokv[j] = (u0 + j < U_DIM) ? tokens[b * U_DIM + u0 + j] : -1;

#pragma unroll 1
  for (int ct = 0; ct < 4; ++ct) {
    const int nbase = ct * 256 + wave * 64;
    ffrag4 acc[3][4];
    ffrag4 zero4 = {0.0f, 0.0f, 0.0f, 0.0f};
#pragma unroll
    for (int rb = 0; rb < 3; ++rb)
#pragma unroll
      for (int cb = 0; cb < 4; ++cb) acc[rb][cb] = zero4;

#pragma unroll 4
    for (int ks = 0; ks < 16; ++ks) {
      const int kchunk = ks * 4 + quad;
      bfrag8 av[3];
#pragma unroll
      for (int rb = 0; rb < 3; ++rb) {
        const int m = rb * 16 + l15;
        const int slot = (kchunk + m) & 63;
        av[rb] = *(const bfrag8*)&sh.X[m * K_INNER + (slot << 3)];
      }
      bfrag8 bv[4];
#pragma unroll
      for (int cb = 0; cb < 4; ++cb) {
        const int n = nbase + cb * 16 + l15;
        bv[cb] = *(const bfrag8*)(W2f + ((size_t)kchunk * 1024 + n) * 8);
      }
#pragma unroll
      for (int rb = 0; rb < 3; ++rb)
#pragma unroll
        for (int cb = 0; cb < 4; ++cb)
          acc[rb][cb] = __builtin_amdgcn_mfma_f32_16x16x32_bf16(av[rb], bv[cb], acc[rb][cb], 0, 0, 0);
    }

    // epilogue: online sum(exp) via exp2, raw label capture (b2 folded at the end)
#pragma unroll
    for (int cb = 0; cb < 4; ++cb) {
      const int v = nbase + cb * 16 + l15;
      const float b2v = (v < V_DIM) ? b2[v] : -1e30f;
      const float b2s = b2v * LOG2E;
#pragma unroll
      for (int rb = 0; rb < 3; ++rb)
#pragma unroll
        for (int reg = 0; reg < 4; ++reg) {
          float a = acc[rb][cb][reg];
          sumexp[rb][reg] += exp2f(fmaf(a, LOG2E, b2s));
          labelA[rb][reg] += (v == tokv[reg]) ? a : 0.0f;
        }
    }
    if (nbase == 0) {   // wave 0, ct 0: v==0 column lives on l15==0 lanes of cb 0
#pragma unroll
      for (int rb = 0; rb < 3; ++rb)
#pragma unroll
        for (int reg = 0; reg < 4; ++reg) blankV[rb][reg] = acc[rb][0][reg];
    }
  }

#pragma unroll
  for (int mask = 1; mask <= 8; mask <<= 1) {
#pragma unroll
    for (int rb = 0; rb < 3; ++rb)
#pragma unroll
      for (int reg = 0; reg < 4; ++reg) {
        sumexp[rb][reg] += __shfl_xor(sumexp[rb][reg], mask, 64);
        labelA[rb][reg] += __shfl_xor(labelA[rb][reg], mask, 64);
      }
  }

  __syncthreads();   // X reads done -> reuse union as red[]
  if (l15 == 0) {
#pragma unroll
    for (int rb = 0; rb < 3; ++rb)
#pragma unroll
      for (int reg = 0; reg < 4; ++reg) {
        int row = rb * 16 + quad * 4 + reg;
        sh.red[wave][row][0] = sumexp[rb][reg];
        sh.red[wave][row][1] = blankV[rb][reg];
        sh.red[wave][row][2] = labelA[rb][reg];
      }
  }
  __syncthreads();
  if (tid < ROWS) {
    float S  = sh.red[0][tid][0] + sh.red[1][tid][0] + sh.red[2][tid][0] + sh.red[3][tid][0];
    float Bl = sh.red[0][tid][1] + sh.red[1][tid][1] + sh.red[2][tid][1] + sh.red[3][tid][1];
    float Lb = sh.red[0][tid][2] + sh.red[1][tid][2] + sh.red[2][tid][2] + sh.red[3][tid][2];
    int t = t0 + (tid >> 2);
    int u = u0 + (tid & 3);
    if (t < T_DIM && u < U1) {
      float lse2 = __log2f(S);                 // S = sum(exp(logit))
      int tok = (u < U_DIM) ? tokens[b * U_DIM + u] : 0;
      int d = t + u;
      size_t idx = ((size_t)b * ND + d) * DP_PITCH + u;
      // store log2-domain log-probs for the DP
      blankD[idx] = (Bl + b2[0])   * LOG2E - lse2;
      labelD[idx] = (Lb + b2[tok]) * LOG2E - lse2;
    }
  }
}

// ---------------- RNNT DP over diagonals, log2 domain, named-register pipeline
__global__ __launch_bounds__(256)
void dp_kernel(const float* __restrict__ blankD, const float* __restrict__ labelD,
               const int* __restrict__ outLen, const int* __restrict__ tokLen,
               float* __restrict__ outLoss)
{
  __shared__ float llsh[B_DIM];
  const int tid = threadIdx.x;
  const int wv = tid >> 6;
  const int lane = tid & 63;
  const float* bD = blankD + (size_t)wv * ND * DP_PITCH;
  const float* lD = labelD + (size_t)wv * ND * DP_PITCH;
  const int tIdx = outLen[wv] - 1;
  const int uIdx = tokLen[wv];
  const int dStar = tIdx + uIdx;
  const float NEG = -1e30f;

  float aE = (lane == 0) ? 0.0f : NEG;   // log2(1) = 0
  float aO = NEG;
  float ll2 = 0.0f;
  if (dStar == 0 && lane == 0) ll2 = bD[0];

  const int uE = 2 * lane, uO = uE + 1;

#define LDB(dg) (*(const float2*)&bD[(size_t)(dg) * DP_PITCH + uE])
#define LDL(dg) (*(const float2*)&lD[(size_t)(dg) * DP_PITCH + uE])

  float2 B0 = LDB(0), L0 = LDL(0);
  float2 B1 = LDB(1), L1 = LDL(1);
  float2 B2 = LDB(2), L2 = LDL(2);
  float2 B3 = LDB(3), L3 = LDL(3);

#define DPSTEP(d, Bv, Lv)                                                    \
  {                                                                          \
    float aO_up = __shfl_up(aO, 1, 64);                                      \
    if (lane == 0) aO_up = NEG;                                              \
    float labUp = __shfl_up(Lv.y, 1, 64);                                    \
    float bt0 = aE + Bv.x, lt0 = aO_up + labUp;                              \
    float mx0 = fmaxf(bt0, lt0), mn0 = fminf(bt0, lt0);                      \
    float r0 = mx0 + __log2f(1.0f + exp2f(mn0 - mx0));                       \
    int te = (d) - uE;                                                       \
    float nE = ((uE <= U_DIM) && (te >= 0) && (te < T_DIM)) ? r0 : NEG;      \
    float bt1 = aO + Bv.y, lt1 = aE + Lv.x;                                  \
    float mx1 = fmaxf(bt1, lt1), mn1 = fminf(bt1, lt1);                      \
    float r1 = mx1 + __log2f(1.0f + exp2f(mn1 - mx1));                       \
    int to = (d) - uO;                                                       \
    float nO = ((uO <= U_DIM) && (to >= 0) && (to < T_DIM)) ? r1 : NEG;      \
    aE = nE; aO = nO;                                                        \
    if ((d) == dStar) {                                                      \
      float blk = bD[(size_t)(d) * DP_PITCH + uIdx];                         \
      if (uIdx == uE)      ll2 = nE + blk;                                   \
      else if (uIdx == uO) ll2 = nO + blk;                                   \
    }                                                                        \
  }

  // groups of 4: base = 1,5,...,293 covers d = 1..296; tail d = 297..299
  for (int base = 1; base <= 293; base += 4) {
    DPSTEP(base + 0, B0, L0); B0 = LDB(base + 3); L0 = LDL(base + 3);
    DPSTEP(base + 1, B1, L1); B1 = LDB(base + 4); L1 = LDL(base + 4);
    DPSTEP(base + 2, B2, L2); B2 = LDB(base + 5); L2 = LDL(base + 5);
    DPSTEP(base + 3, B3, L3); B3 = LDB(base + 6); L3 = LDL(base + 6);
  }
  DPSTEP(297, B0, L0);
  DPSTEP(298, B1, L1);
  DPSTEP(299, B2, L2);

#undef DPSTEP
#undef LDB
#undef LDL

#pragma unroll
  for (int mask = 1; mask < 64; mask <<= 1) ll2 += __shfl_xor(ll2, mask, 64);
  if (lane == 0) llsh[wv] = ll2;
  __syncthreads();
  if (tid == 0)
    outLoss[0] = -(llsh[0] + llsh[1] + llsh[2] + llsh[3]) * 0.25f * LN2;
}

// ---------------- launch
extern "C" void kernel_launch(void* const* d_in, const int* in_sizes, int n_in,
                              void* d_out, int out_size, void* d_ws, size_t ws_size,
                              hipStream_t stream)
{
  const float* enc    = (const float*)d_in[0];
  const float* dec    = (const float*)d_in[1];
  const int*   tokens = (const int*)d_in[2];
  const int*   outLen = (const int*)d_in[3];
  const int*   tokLen = (const int*)d_in[4];
  const float* W1     = (const float*)d_in[5];
  const float* b1     = (const float*)d_in[6];
  const float* W2     = (const float*)d_in[7];
  const float* b2     = (const float*)d_in[8];
  float* out = (float*)d_out;

  char* ws = (char*)d_ws;
  float*    hEnc   = (float*)(ws + 0);           // 800*512*4   = 1,638,400
  float*    hDec   = (float*)(ws + 1638400);     // 404*512*4   =   827,392
  ushort_t* W2f    = (ushort_t*)(ws + 2465792);  // 64*1024*8*2 = 1,048,576
  float*    blankD = (float*)(ws + 3514368);     // 4*300*128*4 =   614,400
  float*    labelD = (float*)(ws + 4128768);     // 4*300*128*4 =   614,400  (end 4,743,168)

  prep_kernel<<<dim3(215), dim3(512), 0, stream>>>(enc, dec, W1, W2, hEnc, hDec, W2f);
  joint_kernel<<<dim3(26, 17, B_DIM), dim3(256), 0, stream>>>(hEnc, hDec, b1, W2f, b2, tokens, blankD, labelD);
  dp_kernel<<<dim3(1), dim3(256), 0, stream>>>(blankD, labelD, outLen, tokLen, out);
}